// Round 14
// baseline (334.830 us; speedup 1.0000x reference)
//
#include <hip/hip_runtime.h>
#include <hip/hip_bf16.h>
#include <cstdint>
#include <cstddef>

#define TT 2048      // tokens (b*t)
#define DD 1024      // d
#define HH 2048      // h
#define NE 16        // experts
#define WM128 48     // max (expert, 128-row block) work items
#define PKTILE 2048  // u16 per panel tile (64 n-rows x 32 k, LDS-image w/ XOR chunk swizzle)

typedef __bf16 bf16x8 __attribute__((ext_vector_type(8)));
typedef float f32x4 __attribute__((ext_vector_type(4)));

__device__ __forceinline__ unsigned short f2bf(float f) {
  union { float f; unsigned u; } v; v.f = f;
  unsigned r = (v.u + 0x7FFFu + ((v.u >> 16) & 1u)) >> 16;  // RNE
  return (unsigned short)r;
}
__device__ __forceinline__ float bf2f(unsigned short s) {
  union { unsigned u; float f; } v; v.u = ((unsigned)s) << 16;
  return v.f;
}
__device__ __forceinline__ unsigned packbf(float lo, float hi) {
  return (unsigned)f2bf(lo) | ((unsigned)f2bf(hi) << 16);
}

__device__ __forceinline__ void gl_lds16(const void* g, void* l) {
  __builtin_amdgcn_global_load_lds(
      (const __attribute__((address_space(1))) unsigned int*)g,
      (__attribute__((address_space(3))) unsigned int*)l, 16, 0, 0);
}

// Counted-vmcnt barrier: wait until <=N VMEM ops outstanding (the N newest,
// i.e. the just-issued next-next-tile stage), LDS visible, then raw barrier.
#define BARRIER_N(N)                                            \
  do {                                                          \
    asm volatile("s_waitcnt vmcnt(" #N ")" ::: "memory");       \
    asm volatile("s_waitcnt lgkmcnt(0)" ::: "memory");          \
    __builtin_amdgcn_sched_barrier(0);                          \
    __builtin_amdgcn_s_barrier();                               \
    __builtin_amdgcn_sched_barrier(0);                          \
  } while (0)

// ---------------- router + top-2 + bucketing + x cvt (fused) ----------------
__global__ __launch_bounds__(256) void k_router(
    const float* __restrict__ x, const float* __restrict__ rw,
    const float* __restrict__ rb, int* __restrict__ cnt,
    int* __restrict__ list_tok, int* __restrict__ rec,
    float* __restrict__ wrec, unsigned short* __restrict__ xbf) {
  const int t = blockIdx.x;
  __shared__ float xs[DD];
  __shared__ float part[256];
  __shared__ float sc[NE];
  const float* xr = x + (size_t)t * DD;
  for (int i = threadIdx.x; i < DD; i += 256) xs[i] = xr[i];
  __syncthreads();
  {
    int i = threadIdx.x * 4;
    ushort4 o = { f2bf(xs[i]), f2bf(xs[i + 1]), f2bf(xs[i + 2]), f2bf(xs[i + 3]) };
    *reinterpret_cast<ushort4*>(xbf + (size_t)t * DD + i) = o;
  }
  const int e = threadIdx.x >> 4, j = threadIdx.x & 15;
  const float* w = rw + (size_t)e * DD;
  float s = 0.f;
  for (int i = j; i < DD; i += 16) s += xs[i] * w[i];
  part[threadIdx.x] = s;
  __syncthreads();
  if (threadIdx.x < NE) {
    float v = rb[threadIdx.x];
    #pragma unroll
    for (int q = 0; q < 16; ++q) v += part[threadIdx.x * 16 + q];
    sc[threadIdx.x] = v;
  }
  __syncthreads();
  if (threadIdx.x == 0) {
    int e1 = 0; float v1 = sc[0];
    #pragma unroll
    for (int q = 1; q < NE; ++q) { if (sc[q] > v1) { v1 = sc[q]; e1 = q; } }
    int e2 = -1; float v2 = -3.4e38f;
    #pragma unroll
    for (int q = 0; q < NE; ++q) {
      if (q != e1 && sc[q] > v2) { v2 = sc[q]; e2 = q; }
    }
    float ex = expf(v2 - v1);
    float w1 = 1.f / (1.f + ex);
    float w2 = ex / (1.f + ex);
    int p1 = atomicAdd(&cnt[e1], 1);
    int p2 = atomicAdd(&cnt[e2], 1);
    list_tok[e1 * TT + p1] = t;
    list_tok[e2 * TT + p2] = t;
    rec[t * 4 + 0] = e1; rec[t * 4 + 1] = p1;
    rec[t * 4 + 2] = e2; rec[t * 4 + 3] = p2;
    wrec[t * 2 + 0] = w1; wrec[t * 2 + 1] = w2;
  }
}

// ---------------- work-table builder ----------------
__global__ void k_sched(const int* __restrict__ cnt, int* __restrict__ work128,
                        int* __restrict__ woff) {
  if (threadIdx.x == 0) {
    int o = 0, n1 = 0;
    for (int e = 0; e < NE; ++e) {
      int ce = cnt[e];
      int a = (ce + 127) >> 7;
      for (int mb = 0; mb < a; ++mb) { work128[n1 * 2] = e; work128[n1 * 2 + 1] = mb; ++n1; }
      woff[e] = o; o += ce;
    }
    for (int q = n1; q < WM128; ++q) { work128[q * 2] = -1; work128[q * 2 + 1] = 0; }
  }
}

// ---------------- weight prepack: fp32 [K][N] -> bf16 LDS-image panels ----------------
// Block = (e, y->(kt,nc), z matrix). Reads 32 k-rows x 512 n fp32 (2 KB contiguous
// per row), k-pair u32 transpose in LDS (conflict-free), writes 8 panels x 4 KB
// contiguous. Panel chunk (row,ch) holds k = kt*32 + 8*(ch ^ ((row>>1)&3)) .. +7
// for n-col = row  (matches k_up/k_down ds_read swizzle; rule-21 source-side XOR).
__global__ __launch_bounds__(256, 4) void k_pack(
    const float* __restrict__ s0, const float* __restrict__ s1,
    unsigned short* __restrict__ d0, unsigned short* __restrict__ d1,
    int zbase) {
  __shared__ unsigned int Bu[512 * 17];   // [n 512][u32 col 17 (16 kp + pad)]
  const int z = zbase + blockIdx.z;
  const int down = (z == 2);
  const int e = blockIdx.x;
  const int K = down ? HH : DD;
  const int N = down ? DD : HH;
  const int kt = down ? ((int)blockIdx.y >> 1) : ((int)blockIdx.y >> 2);
  const int nc = down ? ((int)blockIdx.y & 1) : ((int)blockIdx.y & 3);
  const float* src = (z == 1) ? s1 : s0;
  unsigned short* dst = (z == 1) ? d1 : d0;
  const int tid = threadIdx.x;
  const float* sb = src + (size_t)e * K * N + (size_t)(kt * 32) * N + nc * 512;
  // pack: 2048 pair-slots (nq 0..127, q2 0..15); coalesced 1KB row-segment reads
  #pragma unroll
  for (int s = 0; s < 8; ++s) {
    int slot = s * 256 + tid;
    int nq = slot & 127;
    int q2 = slot >> 7;
    const float* pa = sb + (size_t)(2 * q2) * N + nq * 4;
    float4 a = *reinterpret_cast<const float4*>(pa);
    float4 b = *reinterpret_cast<const float4*>(pa + N);
    const float* af = reinterpret_cast<const float*>(&a);
    const float* bf = reinterpret_cast<const float*>(&b);
    int col = q2 ^ ((nq >> 3) & 7);   // column swizzle: spreads write banks (2-way free)
    #pragma unroll
    for (int i = 0; i < 4; ++i)
      Bu[(4 * nq + i) * 17 + col] = packbf(af[i], bf[i]);
  }
  __syncthreads();
  // readout: 512 rows x 4 chunks; coalesced 4KB-panel contiguous writes
  const int pgrp = down ? 16 : 32;    // panels per expert
  const int ktn  = down ? 64 : 32;    // kt tiles per panel
  #pragma unroll
  for (int s = 0; s < 8; ++s) {
    int idx = s * 256 + tid;
    int r = idx >> 2;                  // n within block (0..511)
    int ch = idx & 3;
    int row = r & 63;                  // n within panel
    int p = r >> 6;                    // panel within block (0..7)
    int ntg = nc * 8 + p;
    int kc = ch ^ ((row >> 1) & 3);    // logical k-chunk for this physical chunk
    int key = (r >> 5) & 7;
    uint4 w;
    w.x = Bu[r * 17 + ((kc * 4 + 0) ^ key)];
    w.y = Bu[r * 17 + ((kc * 4 + 1) ^ key)];
    w.z = Bu[r * 17 + ((kc * 4 + 2) ^ key)];
    w.w = Bu[r * 17 + ((kc * 4 + 3) ^ key)];
    size_t tile = ((size_t)e * pgrp + ntg) * ktn + kt;
    *reinterpret_cast<uint4*>(dst + tile * PKTILE + row * 32 + ch * 8) = w;
  }
}

// ---------------- up GEMMs (mag,freq) + activation — panel path ----------------
// BM=128,BN=64,BK=32; A and B both via gl_lds16 from contiguous sources; LDS
// triple-buffered (stage kt+2 while computing kt), counted vmcnt(4) barriers.
__global__ __launch_bounds__(256, 3) void k_up(
    const unsigned short* __restrict__ xbf,
    const unsigned short* __restrict__ pmag,   // bf16 panels
    const unsigned short* __restrict__ pfreq,  // bf16 panels
    const float* __restrict__ bphase,
    const int* __restrict__ cnt, const int* __restrict__ list_tok,
    const int* __restrict__ work, const int* __restrict__ woff,
    unsigned short* __restrict__ hid) {
  const int e = work[blockIdx.x * 2 + 0];
  if (e < 0) return;
  const int mt = work[blockIdx.x * 2 + 1];
  const int nt = blockIdx.y;
  const int ce = cnt[e];
  const int off = woff[e];
  __shared__ unsigned short As[3][128][32];   // 24 KB
  __shared__ unsigned short Bm[3][64][32];    // 12 KB
  __shared__ unsigned short Bf[3][64][32];    // 12 KB
  __shared__ int toks[128];
  const int tid = threadIdx.x;
  if (tid < 128) {
    int r = mt * 128 + tid;
    toks[tid] = list_tok[e * TT + (r < ce ? r : ce - 1)];
  }
  __syncthreads();
  const int w = tid >> 6, l = tid & 63;
  // A staging: 2 chunks/thread, source-side XOR chunk swizzle (proven)
  size_t abase[2]; int aoff[2];
  #pragma unroll
  for (int p = 0; p < 2; ++p) {
    int row = p * 64 + w * 16 + (l >> 2);
    int g = (l & 3) ^ ((row >> 1) & 3);
    abase[p] = (size_t)toks[row] * DD + g * 8;
    aoff[p] = (p * 256 + w * 64 + l) * 8;
  }
  // B staging: 1 chunk/thread/matrix from panels (linear LDS image)
  const unsigned short* pmb = pmag  + ((size_t)(e * 32 + nt) * 32) * PKTILE + tid * 8;
  const unsigned short* pfb = pfreq + ((size_t)(e * 32 + nt) * 32) * PKTILE + tid * 8;
  const int boff = tid * 8;
  const int n0 = nt * 64;
  const int wm = (w >> 1) * 64, wn = (w & 1) * 32;
  const int lr = l & 15, kg = l >> 4;
  const f32x4 zero = {0.f, 0.f, 0.f, 0.f};
  f32x4 accM[4][2], accF[4][2];
  #pragma unroll
  for (int a = 0; a < 4; ++a)
    #pragma unroll
    for (int b = 0; b < 2; ++b) { accM[a][b] = zero; accF[a][b] = zero; }

  auto stage = [&](int kt, int buf) {
    gl_lds16(xbf + abase[0] + kt * 32, &As[buf][0][0] + aoff[0]);
    gl_lds16(xbf + abase[1] + kt * 32, &As[buf][0][0] + aoff[1]);
    gl_lds16(pmb + (size_t)kt * PKTILE, &Bm[buf][0][0] + boff);
    gl_lds16(pfb + (size_t)kt * PKTILE, &Bf[buf][0][0] + boff);
  };
  auto compute = [&](int buf) {
    bf16x8 av[4], bmv[2], bfv[2];
    #pragma unroll
    for (int fm = 0; fm < 4; ++fm) {
      int row = wm + fm * 16 + lr;
      int c = kg ^ ((row >> 1) & 3);
      av[fm] = *reinterpret_cast<const bf16x8*>(&As[buf][row][c * 8]);
    }
    #pragma unroll
    for (int fn = 0; fn < 2; ++fn) {
      int row = wn + fn * 16 + lr;
      int c = kg ^ ((row >> 1) & 3);
      bmv[fn] = *reinterpret_cast<const bf16x8*>(&Bm[buf][row][c * 8]);
      bfv[fn] = *reinterpret_cast<const bf16x8*>(&Bf[buf][row][c * 8]);
    }
    #pragma unroll
    for (int fm = 0; fm < 4; ++fm)
      #pragma unroll
      for (int fn = 0; fn < 2; ++fn) {
        accM[fm][fn] = __builtin_amdgcn_mfma_f32_16x16x32_bf16(av[fm], bmv[fn], accM[fm][fn], 0, 0, 0);
        accF[fm][fn] = __builtin_amdgcn_mfma_f32_16x16x32_bf16(av[fm], bfv[fn], accF[fm][fn], 0, 0, 0);
      }
  };

  stage(0, 0);
  stage(1, 1);
  BARRIER_N(4);            // certify stage(0); stage(1) still in flight
  for (int kt = 0; kt < 32; ++kt) {
    if (kt + 2 < 32) stage(kt + 2, (kt + 2) % 3);
    compute(kt % 3);
    if (kt == 31) break;
    if (kt + 2 < 32) { BARRIER_N(4); } else { BARRIER_N(0); }
  }
  // epilogue: activation + store
  #pragma unroll
  for (int fn = 0; fn < 2; ++fn) {
    const int ng = n0 + wn + fn * 16 + lr;
    const float ph = bphase[e * HH + ng] + 0.1f;
    #pragma unroll
    for (int fm = 0; fm < 4; ++fm) {
      #pragma unroll
      for (int jj = 0; jj < 4; ++jj) {
        int m = mt * 128 + wm + fm * 16 + kg * 4 + jj;
        if (m < ce) {
          float mv = accM[fm][fn][jj];
          float fv = accF[fm][fn][jj];
          float exn = __expf(-fabsf(fv));
          float sp = fmaxf(fv, 0.f) + __logf(1.f + exn);   // stable softplus
          float t2 = __expf(2.f * mv);
          float th = 1.f - 2.f / (t2 + 1.f);               // tanh
          float hv = th * __cosf(sp + ph);
          hid[(size_t)(off + m) * HH + ng] = f2bf(hv);
        }
      }
    }
  }
}

// ---------------- down GEMM — panel path ----------------
// BM=128,BN=64,BK=32; 64 phases; triple-buffered, vmcnt(3) barriers.
__global__ __launch_bounds__(256, 4) void k_down(
    const unsigned short* __restrict__ hid,
    const unsigned short* __restrict__ pdown,  // bf16 panels
    const int* __restrict__ cnt,
    const int* __restrict__ work, const int* __restrict__ woff,
    unsigned short* __restrict__ op) {
  const int e = work[blockIdx.x * 2 + 0];
  if (e < 0) return;
  const int mt = work[blockIdx.x * 2 + 1];
  const int nt = blockIdx.y;
  const int ce = cnt[e];
  const int off = woff[e];
  __shared__ unsigned short As[3][128][32];   // 24 KB
  __shared__ unsigned short Bd[3][64][32];    // 12 KB
  const int tid = threadIdx.x;
  const int w = tid >> 6, l = tid & 63;
  size_t abase[2]; int aoff[2];
  #pragma unroll
  for (int p = 0; p < 2; ++p) {
    int row = p * 64 + w * 16 + (l >> 2);
    int g = (l & 3) ^ ((row >> 1) & 3);
    int gr = mt * 128 + row; if (gr >= ce) gr = ce - 1;
    abase[p] = (size_t)(off + gr) * HH + g * 8;
    aoff[p] = (p * 256 + w * 64 + l) * 8;
  }
  const unsigned short* pdb = pdown + ((size_t)(e * 16 + nt) * 64) * PKTILE + tid * 8;
  const int boff = tid * 8;
  const int n0 = nt * 64;
  const int wm = (w >> 1) * 64, wn = (w & 1) * 32;
  const int lr = l & 15, kg = l >> 4;
  const f32x4 zero = {0.f, 0.f, 0.f, 0.f};
  f32x4 acc[4][2];
  #pragma unroll
  for (int a = 0; a < 4; ++a)
    #pragma unroll
    for (int b = 0; b < 2; ++b) acc[a][b] = zero;

  auto stage = [&](int kt, int buf) {
    gl_lds16(hid + abase[0] + kt * 32, &As[buf][0][0] + aoff[0]);
    gl_lds16(hid + abase[1] + kt * 32, &As[buf][0][0] + aoff[1]);
    gl_lds16(pdb + (size_t)kt * PKTILE, &Bd[buf][0][0] + boff);
  };
  auto compute = [&](int buf) {
    bf16x8 av[4], bv[2];
    #pragma unroll
    for (int fm = 0; fm < 4; ++fm) {
      int row = wm + fm * 16 + lr;
      int c = kg ^ ((row >> 1) & 3);
      av[fm] = *reinterpret_cast<const bf16x8*>(&As[buf][row][c * 8]);
    }
    #pragma unroll
    for (int fn = 0; fn < 2; ++fn) {
      int row = wn + fn * 16 + lr;
      int c = kg ^ ((row >> 1) & 3);
      bv[fn] = *reinterpret_cast<const bf16x8*>(&Bd[buf][row][c * 8]);
    }
    #pragma unroll
    for (int fm = 0; fm < 4; ++fm)
      #pragma unroll
      for (int fn = 0; fn < 2; ++fn)
        acc[fm][fn] = __builtin_amdgcn_mfma_f32_16x16x32_bf16(av[fm], bv[fn], acc[fm][fn], 0, 0, 0);
  };

  stage(0, 0);
  stage(1, 1);
  BARRIER_N(3);
  for (int kt = 0; kt < 64; ++kt) {
    if (kt + 2 < 64) stage(kt + 2, (kt + 2) % 3);
    compute(kt % 3);
    if (kt == 63) break;
    if (kt + 2 < 64) { BARRIER_N(3); } else { BARRIER_N(0); }
  }
  #pragma unroll
  for (int fn = 0; fn < 2; ++fn) {
    const int ng = n0 + wn + fn * 16 + lr;
    #pragma unroll
    for (int fm = 0; fm < 4; ++fm) {
      #pragma unroll
      for (int jj = 0; jj < 4; ++jj) {
        int m = mt * 128 + wm + fm * 16 + kg * 4 + jj;
        if (m < ce)
          op[(size_t)(off + m) * DD + ng] = f2bf(acc[fm][fn][jj]);
      }
    }
  }
}

// ---------------- combine + RMSNorm ----------------
__global__ __launch_bounds__(256) void k_norm(
    const unsigned short* __restrict__ op, const int* __restrict__ woff,
    const int* __restrict__ rec, const float* __restrict__ wrec,
    const float* __restrict__ nw, float* __restrict__ out) {
  const int t = blockIdx.x;
  const int tid = threadIdx.x;
  __shared__ float red[4];
  const int e1 = rec[t * 4 + 0], p1 = rec[t * 4 + 1];
  const int e2 = rec[t * 4 + 2], p2 = rec[t * 4 + 3];
  const float w1 = wrec[t * 2 + 0], w2 = wrec[t * 2 + 1];
  const unsigned short* pa = op + (size_t)(woff[e1] + p1) * DD;
  const unsigned short* pb = op + (size_t)(woff[e2] + p2) * DD;
  float v[4]; float ss = 0.f;
  #pragma unroll
  for (int q = 0; q < 4; ++q) {
    int i = q * 256 + tid;
    v[q] = w1 * bf2f(pa[i]) + w2 * bf2f(pb[i]);
    ss += v[q] * v[q];
  }
  #pragma unroll
  for (int o = 32; o > 0; o >>= 1) ss += __shfl_xor(ss, o);
  if ((tid & 63) == 0) red[tid >> 6] = ss;
  __syncthreads();
  const float tot = red[0] + red[1] + red[2] + red[3];
  const float scl = rsqrtf(tot * (1.f / DD) + 1e-6f);
  #pragma unroll
  for (int q = 0; q < 4; ++q) {
    int i = q * 256 + tid;
    out[(size_t)t * DD + i] = v[q] * scl * nw[i];
  }
}

extern "C" void kernel_launch(void* const* d_in, const int* in_sizes, int n_in,
                              void* d_out, int out_size, void* d_ws, size_t ws_size,
                              hipStream_t stream) {
  const float* x      = (const float*)d_in[0];
  const float* rw     = (const float*)d_in[1];
  const float* rb     = (const float*)d_in[2];
  const float* bmag   = (const float*)d_in[3];
  const float* bfreq  = (const float*)d_in[4];
  const float* bphase = (const float*)d_in[5];
  const float* bdown  = (const float*)d_in[6];
  const float* nw     = (const float*)d_in[7];
  float* out = (float*)d_out;
  char* ws = (char*)d_ws;
  const size_t MB = 1024 * 1024;
  int*   cnt    = (int*)(ws + 0);          // 16 int
  int*   work1  = (int*)(ws + 128);        // WM128*2 int
  int*   woff   = (int*)(ws + 2048);       // 16 int
  int*   list   = (int*)(ws + 4096);       // 16*2048 int
  int*   rec    = (int*)(ws + 139264);     // 2048*4 int
  float* wrec   = (float*)(ws + 172032);   // 2048*2 f32
  unsigned short* xbf  = (unsigned short*)(ws + 1 * MB);    // 4 MB
  unsigned short* hid  = (unsigned short*)(ws + 5 * MB);    // 16 MB
  unsigned short* op   = (unsigned short*)(ws + 21 * MB);   // 8 MB
  unsigned short* pmag = (unsigned short*)(ws + 32 * MB);   // 64 MB
  unsigned short* pfrq = (unsigned short*)(ws + 96 * MB);   // 64 MB
  unsigned short* pdwn = pmag;   // alias: pmag consumed by k_up before k_pack(down)

  hipMemsetAsync(cnt, 0, 64, stream);
  k_router<<<TT, 256, 0, stream>>>(x, rw, rb, cnt, list, rec, wrec, xbf);
  k_sched<<<1, 64, 0, stream>>>(cnt, work1, woff);
  k_pack<<<dim3(NE, 128, 2), 256, 0, stream>>>(bmag, bfreq, pmag, pfrq, 0);
  k_up<<<dim3(WM128, HH / 64), 256, 0, stream>>>(xbf, pmag, pfrq, bphase,
                                                 cnt, list, work1, woff, hid);
  k_pack<<<dim3(NE, 128, 1), 256, 0, stream>>>(bdown, bdown, pdwn, pdwn, 2);
  k_down<<<dim3(WM128, DD / 64), 256, 0, stream>>>(hid, pdwn, cnt, work1, woff, op);
  k_norm<<<TT, 256, 0, stream>>>(op, woff, rec, wrec, nw, out);
}

// Round 15
// 263.216 us; speedup vs baseline: 1.2721x; 1.2721x over previous
//
#include <hip/hip_runtime.h>
#include <hip/hip_bf16.h>
#include <cstdint>
#include <cstddef>

#define TT 2048      // tokens (b*t)
#define DD 1024      // d
#define HH 2048      // h
#define NE 16        // experts
#define WM128 48     // max (expert, 128-row block) work items
#define BROW 17      // B-tile row stride in u32 (64 rows x 17): 2-way-free banks both sides

typedef __bf16 bf16x8 __attribute__((ext_vector_type(8)));
typedef float f32x4 __attribute__((ext_vector_type(4)));

__device__ __forceinline__ unsigned short f2bf(float f) {
  union { float f; unsigned u; } v; v.f = f;
  unsigned r = (v.u + 0x7FFFu + ((v.u >> 16) & 1u)) >> 16;  // RNE
  return (unsigned short)r;
}
__device__ __forceinline__ float bf2f(unsigned short s) {
  union { unsigned u; float f; } v; v.u = ((unsigned)s) << 16;
  return v.f;
}
__device__ __forceinline__ unsigned packbf(float lo, float hi) {
  return (unsigned)f2bf(lo) | ((unsigned)f2bf(hi) << 16);
}

__device__ __forceinline__ void gl_lds16(const void* g, void* l) {
  __builtin_amdgcn_global_load_lds(
      (const __attribute__((address_space(1))) unsigned int*)g,
      (__attribute__((address_space(3))) unsigned int*)l, 16, 0, 0);
}

union U4 { unsigned int u[4]; bf16x8 v; };

// Counted-vmcnt barrier: certify own gl_lds landed (N newer B-loads may fly),
// LDS writes visible, then raw s_barrier (no vmcnt(0) drain).
#define BARRIER_N(N)                                            \
  do {                                                          \
    asm volatile("s_waitcnt vmcnt(" #N ")" ::: "memory");       \
    asm volatile("s_waitcnt lgkmcnt(0)" ::: "memory");          \
    __builtin_amdgcn_sched_barrier(0);                          \
    __builtin_amdgcn_s_barrier();                               \
    __builtin_amdgcn_sched_barrier(0);                          \
  } while (0)

// ---------------- router + top-2 + bucketing + x cvt (fused) ----------------
__global__ __launch_bounds__(256) void k_router(
    const float* __restrict__ x, const float* __restrict__ rw,
    const float* __restrict__ rb, int* __restrict__ cnt,
    int* __restrict__ list_tok, int* __restrict__ rec,
    float* __restrict__ wrec, unsigned short* __restrict__ xbf) {
  const int t = blockIdx.x;
  __shared__ float xs[DD];
  __shared__ float part[256];
  __shared__ float sc[NE];
  const float* xr = x + (size_t)t * DD;
  for (int i = threadIdx.x; i < DD; i += 256) xs[i] = xr[i];
  __syncthreads();
  {
    int i = threadIdx.x * 4;
    ushort4 o = { f2bf(xs[i]), f2bf(xs[i + 1]), f2bf(xs[i + 2]), f2bf(xs[i + 3]) };
    *reinterpret_cast<ushort4*>(xbf + (size_t)t * DD + i) = o;
  }
  const int e = threadIdx.x >> 4, j = threadIdx.x & 15;
  const float* w = rw + (size_t)e * DD;
  float s = 0.f;
  for (int i = j; i < DD; i += 16) s += xs[i] * w[i];
  part[threadIdx.x] = s;
  __syncthreads();
  if (threadIdx.x < NE) {
    float v = rb[threadIdx.x];
    #pragma unroll
    for (int q = 0; q < 16; ++q) v += part[threadIdx.x * 16 + q];
    sc[threadIdx.x] = v;
  }
  __syncthreads();
  if (threadIdx.x == 0) {
    int e1 = 0; float v1 = sc[0];
    #pragma unroll
    for (int q = 1; q < NE; ++q) { if (sc[q] > v1) { v1 = sc[q]; e1 = q; } }
    int e2 = -1; float v2 = -3.4e38f;
    #pragma unroll
    for (int q = 0; q < NE; ++q) {
      if (q != e1 && sc[q] > v2) { v2 = sc[q]; e2 = q; }
    }
    float ex = expf(v2 - v1);
    float w1 = 1.f / (1.f + ex);
    float w2 = ex / (1.f + ex);
    int p1 = atomicAdd(&cnt[e1], 1);
    int p2 = atomicAdd(&cnt[e2], 1);
    list_tok[e1 * TT + p1] = t;
    list_tok[e2 * TT + p2] = t;
    rec[t * 4 + 0] = e1; rec[t * 4 + 1] = p1;
    rec[t * 4 + 2] = e2; rec[t * 4 + 3] = p2;
    wrec[t * 2 + 0] = w1; wrec[t * 2 + 1] = w2;
  }
}

// ---------------- work-table builder + XCD-group metadata ----------------
__global__ void k_sched(const int* __restrict__ cnt, int* __restrict__ work128,
                        int* __restrict__ woff, int* __restrict__ nmb,
                        int* __restrict__ flag) {
  if (threadIdx.x == 0) {
    int o = 0, n1 = 0;
    for (int e = 0; e < NE; ++e) {
      int ce = cnt[e];
      int a = (ce + 127) >> 7;
      nmb[e] = a;
      for (int mb = 0; mb < a; ++mb) { work128[n1 * 2] = e; work128[n1 * 2 + 1] = mb; ++n1; }
      woff[e] = o; o += ce;
    }
    for (int q = n1; q < WM128; ++q) { work128[q * 2] = -1; work128[q * 2 + 1] = 0; }
    int f = 0;
    for (int xq = 0; xq < 8; ++xq)
      if (nmb[xq] + nmb[xq + 8] > 6) f = 1;   // per-XCD capacity overflow
    flag[0] = f;
  }
}

// Map linear block id -> (e, mt, nt) so that all nt-members of an (e, mt) group
// share one XCD (L % 8); expert e lives on XCD e % 8. NTL = nt count (32 or 16).
__device__ __forceinline__ bool xcd_map(int L, const int* nmb, const int* flag,
                                        const int* work, int NTSH,
                                        int& e, int& mt, int& nt) {
  if (flag[0] == 0) {
    int x = L & 7, r = L >> 3;
    int m0 = nmb[x] << NTSH, m1 = nmb[x + 8] << NTSH;
    if (r < m0) { e = x; mt = r >> NTSH; nt = r & ((1 << NTSH) - 1); return true; }
    r -= m0;
    if (r < m1) { e = x + 8; mt = r >> NTSH; nt = r & ((1 << NTSH) - 1); return true; }
    return false;
  } else {
    int wq = L >> NTSH;
    e = work[wq * 2];
    if (e < 0) return false;
    mt = work[wq * 2 + 1];
    nt = L & ((1 << NTSH) - 1);
    return true;
  }
}

// ---------------- up GEMMs (mag,freq) + activation ----------------
// R13 body (BK=32, counted vmcnt, 2-deep named B sets, launch_bounds(256,3));
// XCD-grouped block mapping is the ONLY change.
__global__ __launch_bounds__(256, 3) void k_up(
    const unsigned short* __restrict__ xbf,
    const float* __restrict__ bmag,    // [e][DD][HH]
    const float* __restrict__ bfreq,   // [e][DD][HH]
    const float* __restrict__ bphase,
    const int* __restrict__ cnt, const int* __restrict__ list_tok,
    const int* __restrict__ work, const int* __restrict__ woff,
    const int* __restrict__ nmb, const int* __restrict__ flag,
    unsigned short* __restrict__ hid) {
  int e, mt, nt;
  if (!xcd_map(blockIdx.x, nmb, flag, work, 5, e, mt, nt)) return;
  const int ce = cnt[e];
  const int off = woff[e];
  __shared__ unsigned short As[2][128][32];   // 16 KB
  __shared__ unsigned int BuM[2][64 * BROW];  // 8.5 KB
  __shared__ unsigned int BuF[2][64 * BROW];  // 8.5 KB
  __shared__ int toks[128];
  const int tid = threadIdx.x;
  if (tid < 128) {
    int r = mt * 128 + tid;
    toks[tid] = list_tok[e * TT + (r < ce ? r : ce - 1)];
  }
  __syncthreads();
  const int w = tid >> 6, l = tid & 63;
  size_t abase[2]; int aoff[2];
  #pragma unroll
  for (int p = 0; p < 2; ++p) {
    int row = p * 64 + w * 16 + (l >> 2);
    int g = (l & 3) ^ ((row >> 1) & 3);
    abase[p] = (size_t)toks[row] * DD + g * 8;
    aoff[p] = (p * 256 + w * 64 + l) * 8;
  }
  const int q2 = tid >> 4;
  const int b16 = tid & 15;
  const int n0 = nt * 64;
  const float* srcM = bmag  + (size_t)e * DD * HH + n0 + 4 * b16;
  const float* srcF = bfreq + (size_t)e * DD * HH + n0 + 4 * b16;
  int bwv[4];
  #pragma unroll
  for (int i = 0; i < 4; ++i) bwv[i] = (4 * b16 + i) * BROW + q2;

  const int wm = (w >> 1) * 64, wn = (w & 1) * 32;
  const int lr = l & 15, kg = l >> 4;
  const f32x4 zero = {0.f, 0.f, 0.f, 0.f};
  f32x4 accM[4][2], accF[4][2];
  #pragma unroll
  for (int a = 0; a < 4; ++a)
    #pragma unroll
    for (int b = 0; b < 2; ++b) { accM[a][b] = zero; accF[a][b] = zero; }

  float4 Am0, Am1, Af0, Af1;   // set A
  float4 Bm0, Bm1, Bf0, Bf1;   // set B

  auto glA = [&](int kt, int buf) {
    #pragma unroll
    for (int j = 0; j < 2; ++j)
      gl_lds16(xbf + abase[j] + kt * 32, &As[buf][0][0] + aoff[j]);
  };
  auto loadBA = [&](int kt) {
    const float* pM = srcM + (size_t)(kt * 32 + 2 * q2) * HH;
    const float* pF = srcF + (size_t)(kt * 32 + 2 * q2) * HH;
    Am0 = *reinterpret_cast<const float4*>(pM);
    Am1 = *reinterpret_cast<const float4*>(pM + HH);
    Af0 = *reinterpret_cast<const float4*>(pF);
    Af1 = *reinterpret_cast<const float4*>(pF + HH);
  };
  auto loadBB = [&](int kt) {
    const float* pM = srcM + (size_t)(kt * 32 + 2 * q2) * HH;
    const float* pF = srcF + (size_t)(kt * 32 + 2 * q2) * HH;
    Bm0 = *reinterpret_cast<const float4*>(pM);
    Bm1 = *reinterpret_cast<const float4*>(pM + HH);
    Bf0 = *reinterpret_cast<const float4*>(pF);
    Bf1 = *reinterpret_cast<const float4*>(pF + HH);
  };
  auto writeBA = [&](int buf) {
    const float* m0 = reinterpret_cast<const float*>(&Am0);
    const float* m1 = reinterpret_cast<const float*>(&Am1);
    const float* f0 = reinterpret_cast<const float*>(&Af0);
    const float* f1 = reinterpret_cast<const float*>(&Af1);
    #pragma unroll
    for (int i = 0; i < 4; ++i) {
      BuM[buf][bwv[i]] = packbf(m0[i], m1[i]);
      BuF[buf][bwv[i]] = packbf(f0[i], f1[i]);
    }
  };
  auto writeBB = [&](int buf) {
    const float* m0 = reinterpret_cast<const float*>(&Bm0);
    const float* m1 = reinterpret_cast<const float*>(&Bm1);
    const float* f0 = reinterpret_cast<const float*>(&Bf0);
    const float* f1 = reinterpret_cast<const float*>(&Bf1);
    #pragma unroll
    for (int i = 0; i < 4; ++i) {
      BuM[buf][bwv[i]] = packbf(m0[i], m1[i]);
      BuF[buf][bwv[i]] = packbf(f0[i], f1[i]);
    }
  };
  auto compute = [&](int buf) {
    bf16x8 av[4];
    #pragma unroll
    for (int fm = 0; fm < 4; ++fm) {
      int row = wm + fm * 16 + lr;
      int c = kg ^ ((row >> 1) & 3);
      av[fm] = *reinterpret_cast<const bf16x8*>(&As[buf][row][c * 8]);
    }
    U4 tm[2], tf[2];
    #pragma unroll
    for (int fn = 0; fn < 2; ++fn) {
      const int nb = (wn + fn * 16 + lr) * BROW + kg * 4;
      #pragma unroll
      for (int j2 = 0; j2 < 4; ++j2) {
        tm[fn].u[j2] = BuM[buf][nb + j2];
        tf[fn].u[j2] = BuF[buf][nb + j2];
      }
    }
    #pragma unroll
    for (int fm = 0; fm < 4; ++fm)
      #pragma unroll
      for (int fn = 0; fn < 2; ++fn) {
        accM[fm][fn] = __builtin_amdgcn_mfma_f32_16x16x32_bf16(av[fm], tm[fn].v, accM[fm][fn], 0, 0, 0);
        accF[fm][fn] = __builtin_amdgcn_mfma_f32_16x16x32_bf16(av[fm], tf[fn].v, accF[fm][fn], 0, 0, 0);
      }
  };

  glA(0, 0);
  __builtin_amdgcn_sched_barrier(0);
  loadBA(0);
  loadBB(1);
  writeBA(0);
  BARRIER_N(4);
  for (int kt = 0; kt < 32; kt += 2) {
    glA(kt + 1, 1);
    __builtin_amdgcn_sched_barrier(0);
    loadBA(kt + 2 < 32 ? kt + 2 : 31);
    compute(0);
    writeBB(1);
    BARRIER_N(4);
    const bool more = kt + 2 < 32;
    if (more) {
      glA(kt + 2, 0);
      __builtin_amdgcn_sched_barrier(0);
      loadBB(kt + 3 < 32 ? kt + 3 : 31);
    }
    compute(1);
    if (more) {
      writeBA(0);
      BARRIER_N(4);
    }
  }
  #pragma unroll
  for (int fn = 0; fn < 2; ++fn) {
    const int ng = n0 + wn + fn * 16 + lr;
    const float ph = bphase[e * HH + ng] + 0.1f;
    #pragma unroll
    for (int fm = 0; fm < 4; ++fm) {
      #pragma unroll
      for (int jj = 0; jj < 4; ++jj) {
        int m = mt * 128 + wm + fm * 16 + kg * 4 + jj;
        if (m < ce) {
          float mv = accM[fm][fn][jj];
          float fv = accF[fm][fn][jj];
          float exn = __expf(-fabsf(fv));
          float sp = fmaxf(fv, 0.f) + __logf(1.f + exn);   // stable softplus
          float t2 = __expf(2.f * mv);
          float th = 1.f - 2.f / (t2 + 1.f);               // tanh
          float hv = th * __cosf(sp + ph);
          hid[(size_t)(off + m) * HH + ng] = f2bf(hv);
        }
      }
    }
  }
}

// ---------------- down GEMM ----------------
// R13 body; XCD-grouped mapping (16 nt-members per group).
__global__ __launch_bounds__(256, 4) void k_down(
    const unsigned short* __restrict__ hid,
    const float* __restrict__ bdown,   // [e][HH][DD]
    const int* __restrict__ cnt,
    const int* __restrict__ work, const int* __restrict__ woff,
    const int* __restrict__ nmb, const int* __restrict__ flag,
    unsigned short* __restrict__ op) {
  int e, mt, nt;
  if (!xcd_map(blockIdx.x, nmb, flag, work, 4, e, mt, nt)) return;
  const int ce = cnt[e];
  const int off = woff[e];
  __shared__ unsigned short As[2][128][32];   // 16 KB
  __shared__ unsigned int Bu[2][64 * BROW];   // 8.5 KB
  const int tid = threadIdx.x;
  const int w = tid >> 6, l = tid & 63;
  size_t abase[2]; int aoff[2];
  #pragma unroll
  for (int p = 0; p < 2; ++p) {
    int row = p * 64 + w * 16 + (l >> 2);
    int g = (l & 3) ^ ((row >> 1) & 3);
    int gr = mt * 128 + row; if (gr >= ce) gr = ce - 1;
    abase[p] = (size_t)(off + gr) * HH + g * 8;
    aoff[p] = (p * 256 + w * 64 + l) * 8;
  }
  const int q2 = tid >> 4;
  const int b16 = tid & 15;
  const int n0 = nt * 64;
  const float* srcD = bdown + (size_t)e * HH * DD + n0 + 4 * b16;
  int bwv[4];
  #pragma unroll
  for (int i = 0; i < 4; ++i) bwv[i] = (4 * b16 + i) * BROW + q2;

  const int wm = (w >> 1) * 64, wn = (w & 1) * 32;
  const int lr = l & 15, kg = l >> 4;
  const f32x4 zero = {0.f, 0.f, 0.f, 0.f};
  f32x4 acc[4][2];
  #pragma unroll
  for (int a = 0; a < 4; ++a)
    #pragma unroll
    for (int b = 0; b < 2; ++b) acc[a][b] = zero;

  float4 Ad0, Ad1;   // set A
  float4 Bd0, Bd1;   // set B

  auto glA = [&](int kt, int buf) {
    #pragma unroll
    for (int j = 0; j < 2; ++j)
      gl_lds16(hid + abase[j] + kt * 32, &As[buf][0][0] + aoff[j]);
  };
  auto loadBA = [&](int kt) {
    const float* pD = srcD + (size_t)(kt * 32 + 2 * q2) * DD;
    Ad0 = *reinterpret_cast<const float4*>(pD);
    Ad1 = *reinterpret_cast<const float4*>(pD + DD);
  };
  auto loadBB = [&](int kt) {
    const float* pD = srcD + (size_t)(kt * 32 + 2 * q2) * DD;
    Bd0 = *reinterpret_cast<const float4*>(pD);
    Bd1 = *reinterpret_cast<const float4*>(pD + DD);
  };
  auto writeBA = [&](int buf) {
    const float* d0 = reinterpret_cast<const float*>(&Ad0);
    const float* d1 = reinterpret_cast<const float*>(&Ad1);
    #pragma unroll
    for (int i = 0; i < 4; ++i) Bu[buf][bwv[i]] = packbf(d0[i], d1[i]);
  };
  auto writeBB = [&](int buf) {
    const float* d0 = reinterpret_cast<const float*>(&Bd0);
    const float* d1 = reinterpret_cast<const float*>(&Bd1);
    #pragma unroll
    for (int i = 0; i < 4; ++i) Bu[buf][bwv[i]] = packbf(d0[i], d1[i]);
  };
  auto compute = [&](int buf) {
    bf16x8 av[4];
    #pragma unroll
    for (int fm = 0; fm < 4; ++fm) {
      int row = wm + fm * 16 + lr;
      int c = kg ^ ((row >> 1) & 3);
      av[fm] = *reinterpret_cast<const bf16x8*>(&As[buf][row][c * 8]);
    }
    U4 t[2];
    #pragma unroll
    for (int fn = 0; fn < 2; ++fn) {
      const int nb = (wn + fn * 16 + lr) * BROW + kg * 4;
      #pragma unroll
      for (int j2 = 0; j2 < 4; ++j2) t[fn].u[j2] = Bu[buf][nb + j2];
    }
    #pragma unroll
    for (int fm = 0; fm < 4; ++fm)
      #pragma unroll
      for (int fn = 0; fn < 2; ++fn)
        acc[fm][fn] = __builtin_amdgcn_mfma_f32_16x16x32_bf16(av[fm], t[fn].v, acc[fm][fn], 0, 0, 0);
  };

  glA(0, 0);
  __builtin_amdgcn_sched_barrier(0);
  loadBA(0);
  loadBB(1);
  writeBA(0);
  BARRIER_N(2);
  for (int kt = 0; kt < 64; kt += 2) {
    glA(kt + 1, 1);
    __builtin_amdgcn_sched_barrier(0);
    loadBA(kt + 2 < 64 ? kt + 2 : 63);
    compute(0);
    writeBB(1);
    BARRIER_N(2);
    const bool more = kt + 2 < 64;
    if (more) {
      glA(kt + 2, 0);
      __builtin_amdgcn_sched_barrier(0);
      loadBB(kt + 3 < 64 ? kt + 3 : 63);
    }
    compute(1);
    if (more) {
      writeBA(0);
      BARRIER_N(2);
    }
  }
  #pragma unroll
  for (int fn = 0; fn < 2; ++fn) {
    const int ng = n0 + wn + fn * 16 + lr;
    #pragma unroll
    for (int fm = 0; fm < 4; ++fm) {
      #pragma unroll
      for (int jj = 0; jj < 4; ++jj) {
        int m = mt * 128 + wm + fm * 16 + kg * 4 + jj;
        if (m < ce)
          op[(size_t)(off + m) * DD + ng] = f2bf(acc[fm][fn][jj]);
      }
    }
  }
}

// ---------------- combine + RMSNorm ----------------
__global__ __launch_bounds__(256) void k_norm(
    const unsigned short* __restrict__ op, const int* __restrict__ woff,
    const int* __restrict__ rec, const float* __restrict__ wrec,
    const float* __restrict__ nw, float* __restrict__ out) {
  const int t = blockIdx.x;
  const int tid = threadIdx.x;
  __shared__ float red[4];
  const int e1 = rec[t * 4 + 0], p1 = rec[t * 4 + 1];
  const int e2 = rec[t * 4 + 2], p2 = rec[t * 4 + 3];
  const float w1 = wrec[t * 2 + 0], w2 = wrec[t * 2 + 1];
  const unsigned short* pa = op + (size_t)(woff[e1] + p1) * DD;
  const unsigned short* pb = op + (size_t)(woff[e2] + p2) * DD;
  float v[4]; float ss = 0.f;
  #pragma unroll
  for (int q = 0; q < 4; ++q) {
    int i = q * 256 + tid;
    v[q] = w1 * bf2f(pa[i]) + w2 * bf2f(pb[i]);
    ss += v[q] * v[q];
  }
  #pragma unroll
  for (int o = 32; o > 0; o >>= 1) ss += __shfl_xor(ss, o);
  if ((tid & 63) == 0) red[tid >> 6] = ss;
  __syncthreads();
  const float tot = red[0] + red[1] + red[2] + red[3];
  const float scl = rsqrtf(tot * (1.f / DD) + 1e-6f);
  #pragma unroll
  for (int q = 0; q < 4; ++q) {
    int i = q * 256 + tid;
    out[(size_t)t * DD + i] = v[q] * scl * nw[i];
  }
}

extern "C" void kernel_launch(void* const* d_in, const int* in_sizes, int n_in,
                              void* d_out, int out_size, void* d_ws, size_t ws_size,
                              hipStream_t stream) {
  const float* x      = (const float*)d_in[0];
  const float* rw     = (const float*)d_in[1];
  const float* rb     = (const float*)d_in[2];
  const float* bmag   = (const float*)d_in[3];
  const float* bfreq  = (const float*)d_in[4];
  const float* bphase = (const float*)d_in[5];
  const float* bdown  = (const float*)d_in[6];
  const float* nw     = (const float*)d_in[7];
  float* out = (float*)d_out;
  char* ws = (char*)d_ws;
  const size_t MB = 1024 * 1024;
  int*   cnt    = (int*)(ws + 0);          // 16 int
  int*   work1  = (int*)(ws + 128);        // WM128*2 int
  int*   woff   = (int*)(ws + 2048);       // 16 int
  int*   nmb    = (int*)(ws + 2176);       // 16 int
  int*   flag   = (int*)(ws + 2304);       // 1 int
  int*   list   = (int*)(ws + 4096);       // 16*2048 int
  int*   rec    = (int*)(ws + 139264);     // 2048*4 int
  float* wrec   = (float*)(ws + 172032);   // 2048*2 f32
  unsigned short* xbf = (unsigned short*)(ws + 1 * MB);    // 4 MB
  unsigned short* hid = (unsigned short*)(ws + 5 * MB);    // 16 MB
  unsigned short* op  = (unsigned short*)(ws + 21 * MB);   // 8 MB

  hipMemsetAsync(cnt, 0, 64, stream);
  k_router<<<TT, 256, 0, stream>>>(x, rw, rb, cnt, list, rec, wrec, xbf);
  k_sched<<<1, 64, 0, stream>>>(cnt, work1, woff, nmb, flag);
  k_up<<<WM128 * 32, 256, 0, stream>>>(xbf, bmag, bfreq, bphase,
                                       cnt, list, work1, woff, nmb, flag, hid);
  k_down<<<WM128 * 16, 256, 0, stream>>>(hid, bdown, cnt, work1, woff, nmb, flag, op);
  k_norm<<<TT, 256, 0, stream>>>(op, woff, rec, wrec, nw, out);
}